// Round 12
// baseline (132.196 us; speedup 1.0000x reference)
//
#include <hip/hip_runtime.h>

#define TT 1024
#define CC 128
#define LL 128
#define EPSF 1e-7f
#define LN2F 0.69314718055994531f

#define LOG2F(x) __builtin_amdgcn_logf(x)

typedef unsigned int uint;

template <int CTRL>
__device__ __forceinline__ int dpp_i(int old_, int x) {
  return __builtin_amdgcn_update_dpp(old_, x, CTRL, 0xf, 0xf, false);
}
// DPP with bound_ctrl: invalid lanes read 0 (for additive reductions)
template <int CTRL>
__device__ __forceinline__ float dpp0f(float x) {
  return __uint_as_float((uint)__builtin_amdgcn_update_dpp(
      0, (int)__float_as_uint(x), CTRL, 0xf, 0xf, true));
}
// shift a3 to next lane (wave_shr:1); lane 0 receives 0.0f via bound_ctrl
__device__ __forceinline__ float dpp_shr1_f32(float x) {
  return __uint_as_float((uint)__builtin_amdgcn_update_dpp(
      0, (int)__float_as_uint(x), 0x138, 0xf, 0xf, true));
}
__device__ __forceinline__ float readlane63_f(float v) {
  return __uint_as_float(
      (uint)__builtin_amdgcn_readlane((int)__float_as_uint(v), 63));
}

// fp32 -> bf16 bits, round-to-nearest-even (inputs finite positive)
__device__ __forceinline__ uint bf16bits(float x) {
  uint u = __float_as_uint(x);
  return (u + 0x7fffu + ((u >> 16) & 1u)) >> 16;
}

// ---- fused CTC: producer waves feed the serial scan through LDS ----
// 128 blocks x 256 threads (4 waves). Wave 0 = the r5 consumer, UNCHANGED
// (proven 3060cy/32-step pace), ALONE on SIMD0. Waves 1..3 = producers
// staging the 4-buffer LDS ring + EB (barrier per interval publishes).
//
// r11 post-mortem: VGPR stayed 52 and interval stayed ~4850cy. The flaw:
// LOADBUF was placed immediately BEFORE the closing barrier, and the
// barrier's implicit vmcnt(0) drain put ~900cy of fresh HBM latency
// inside the barrier — holding the consumer hostage every interval. Fix:
// issue loads at the START of the producer interval into a SECOND
// register set (double-buffered staging, unroll the interval loop by 2:
// even kk comps set ABC + loads set DEF, odd kk swaps). Each load batch
// then has ~1500+cy (producer comp + consumer-bound barrier wait) before
// its drain -> vmcnt(0) at barrier ~free. 48 staging floats live across
// the barrier: expected VGPR ~80-100 (the diagnostic). Consumer
// byte-identical; numerics bit-identical.

// one lattice step using word wv (bf16 pair) and blank prob pbf
#define CTC_STEP(wv, pbf)                                   \
  do {                                                      \
    const float p1 = __uint_as_float((wv) << 16);           \
    const float p2 = __uint_as_float((wv) & 0xffff0000u);   \
    const float pb = (pbf);                                 \
    const float p3 = dpp_shr1_f32(a3);                      \
    const float n0 = (a0 + p3) * pb;                        \
    const float n1 = __builtin_fmaf(s1f, p3, a0 + a1) * p1; \
    const float n2 = (a2 + a1) * pb;                        \
    const float n3 = __builtin_fmaf(s3f, a1, a3 + a2) * p2; \
    const float n4 = (a4 + a3) * pb;                        \
    a0 = n0; a1 = n1; a2 = n2; a3 = n3; a4 = n4;            \
  } while (0)

#define CTC_QUAD(et, eb)      \
  do {                        \
    CTC_STEP((et).x, (eb).x); \
    CTC_STEP((et).y, (eb).y); \
    CTC_STEP((et).z, (eb).z); \
    CTC_STEP((et).w, (eb).w); \
  } while (0)

// rescale wave-max exponent back to 2^100 (biased 227); e clamped so the
// correction factor stays a normal fp32 even after a catastrophic window
#define CTC_RESCALE()                                                \
  do {                                                               \
    const float m = fmaxf(fmaxf(fmaxf(a0, a1), fmaxf(a2, a3)), a4);  \
    int ke = (int)(__float_as_uint(m) >> 23);                        \
    ke = max(ke, dpp_i<0x111>(ke, ke));                              \
    ke = max(ke, dpp_i<0x112>(ke, ke));                              \
    ke = max(ke, dpp_i<0x114>(ke, ke));                              \
    ke = max(ke, dpp_i<0x118>(ke, ke));                              \
    ke = max(ke, dpp_i<0x142>(ke, ke));                              \
    ke = max(ke, dpp_i<0x143>(ke, ke));                              \
    ke = __builtin_amdgcn_readlane(ke, 63);                          \
    int e = ke - 227; /* biased_exp(max) - (127 + 100) */            \
    e = e < -127 ? -127 : e;                                         \
    const float sc = __uint_as_float((uint)(127 - e) << 23);         \
    a0 *= sc; a1 *= sc; a2 *= sc; a3 *= sc; a4 *= sc;                \
    ell += e;                                                        \
  } while (0)

// load the 4 rows of quad qg into named float2 set S
#define ST_LOAD(S, qg)                                          \
  do {                                                          \
    const float* Pq = Pb + (size_t)(qg) * 4 * CC + 2 * L;       \
    vv##S##0 = *(const float2*)(Pq + 0 * CC);                   \
    vv##S##1 = *(const float2*)(Pq + 1 * CC);                   \
    vv##S##2 = *(const float2*)(Pq + 2 * CC);                   \
    vv##S##3 = *(const float2*)(Pq + 3 * CC);                   \
  } while (0)

// compute + publish quad qg from set S: interleaved DPP row sums (VALU
// only; total in lane 63), normalize, pack bf16|bf16, ONE bperm per
// label + half-select, one ds_write_b128; lane 63 writes blank float4.
#define ST_COMP(S, qg)                                                      \
  do {                                                                      \
    const float2 vr0 = vv##S##0, vr1 = vv##S##1;                            \
    const float2 vr2 = vv##S##2, vr3 = vv##S##3;                            \
    const float2 vr[4] = {vr0, vr1, vr2, vr3};                              \
    float ss[4];                                                            \
    ss[0] = (vr0.x + vr0.y) + (2.0f * EPSF);                                \
    ss[1] = (vr1.x + vr1.y) + (2.0f * EPSF);                                \
    ss[2] = (vr2.x + vr2.y) + (2.0f * EPSF);                                \
    ss[3] = (vr3.x + vr3.y) + (2.0f * EPSF);                                \
    _Pragma("unroll") for (int j = 0; j < 4; ++j)                           \
        ss[j] += dpp0f<0x111>(ss[j]); /* row_shr:1 */                       \
    _Pragma("unroll") for (int j = 0; j < 4; ++j)                           \
        ss[j] += dpp0f<0x112>(ss[j]); /* row_shr:2 */                       \
    _Pragma("unroll") for (int j = 0; j < 4; ++j)                           \
        ss[j] += dpp0f<0x114>(ss[j]); /* row_shr:4 */                       \
    _Pragma("unroll") for (int j = 0; j < 4; ++j)                           \
        ss[j] += dpp0f<0x118>(ss[j]); /* row_shr:8 */                       \
    _Pragma("unroll") for (int j = 0; j < 4; ++j)                           \
        ss[j] += dpp0f<0x142>(ss[j]); /* row_bcast15 */                     \
    _Pragma("unroll") for (int j = 0; j < 4; ++j)                           \
        ss[j] += dpp0f<0x143>(ss[j]); /* row_bcast31: total in lane 63 */   \
    uint wds[4];                                                            \
    float nys[4];                                                           \
    _Pragma("unroll") for (int j = 0; j < 4; ++j) {                         \
      const float r = 1.0f / readlane63_f(ss[j]);                           \
      const float er = EPSF * r;                                            \
      const float nx = __builtin_fmaf(vr[j].x, r, er);                      \
      const float ny = __builtin_fmaf(vr[j].y, r, er);                      \
      const uint pk = (bf16bits(ny) << 16) | bf16bits(nx);                  \
      const uint wx = (uint)__builtin_amdgcn_ds_bpermute(gxb, (int)pk);     \
      const uint wy = (uint)__builtin_amdgcn_ds_bpermute(gyb, (int)pk);     \
      const uint bx = sx ? (wx >> 16) : (wx & 0xffffu);                     \
      const uint by = sy ? (wy >> 16) : (wy & 0xffffu);                     \
      wds[j] = (by << 16) | bx;                                             \
      nys[j] = ny;                                                          \
    }                                                                       \
    uint4 val;                                                              \
    val.x = wds[0]; val.y = wds[1]; val.z = wds[2]; val.w = wds[3];         \
    *(uint4*)((char*)ETl + (((qg) >> 3) & 3) * 8192 +                       \
              ((qg) & 7) * 1024 + L * 16) = val;                            \
    if (L == 63) {                                                          \
      float4 e4;                                                            \
      e4.x = nys[0]; e4.y = nys[1]; e4.z = nys[2]; e4.w = nys[3];           \
      *(float4*)&EBl[(qg) * 4] = e4;                                        \
    }                                                                       \
  } while (0)

// per-wave quad ownership within buffer bb: q = (w-1), (w-1)+3, (w-1)+6
#define LOADBUF3(X, Y, Z, bb)         \
  do {                                \
    const int qb = (bb) * 8 + w - 1;  \
    ST_LOAD(X, qb);                   \
    ST_LOAD(Y, qb + 3);               \
    if (w < 3) ST_LOAD(Z, qb + 6);    \
  } while (0)
#define COMPBUF3(X, Y, Z, bb)         \
  do {                                \
    const int qb = (bb) * 8 + w - 1;  \
    ST_COMP(X, qb);                   \
    ST_COMP(Y, qb + 3);               \
    if (w < 3) ST_COMP(Z, qb + 6);    \
  } while (0)

// consumer interval: 8 groups of buffer kk_, 1-group-ahead A/B rotation
#define CONSUME(kk_)                                                     \
  do {                                                                   \
    const uint4* cur = (const uint4*)ETl + (size_t)((kk_) & 3) * 512;    \
    const float4* ebp = (const float4*)&EBl[(kk_) * 32];                 \
    etB = cur[1 * 64 + L]; ebB = ebp[1];                                 \
    CTC_QUAD(etA, ebA); /* g0 */                                         \
    etA = cur[2 * 64 + L]; ebA = ebp[2];                                 \
    CTC_QUAD(etB, ebB); /* g1 */                                         \
    etB = cur[3 * 64 + L]; ebB = ebp[3];                                 \
    CTC_QUAD(etA, ebA); /* g2 */                                         \
    etA = cur[4 * 64 + L]; ebA = ebp[4];                                 \
    CTC_QUAD(etB, ebB); /* g3 */                                         \
    CTC_RESCALE();                                                       \
    etB = cur[5 * 64 + L]; ebB = ebp[5];                                 \
    CTC_QUAD(etA, ebA); /* g4 */                                         \
    etA = cur[6 * 64 + L]; ebA = ebp[6];                                 \
    CTC_QUAD(etB, ebB); /* g5 */                                         \
    etB = cur[7 * 64 + L]; ebB = ebp[7];                                 \
    CTC_QUAD(etA, ebA); /* g6 */                                         \
    etA = ((const uint4*)ETl)[(size_t)(((kk_) + 1) & 3) * 512 + L];      \
    ebA = *(const float4*)&EBl[((kk_) < 31) ? ((kk_) + 1) * 32 : 1020];  \
    CTC_QUAD(etB, ebB); /* g7 */                                         \
    CTC_RESCALE();                                                       \
  } while (0)

__global__ __launch_bounds__(256) void ctc_fused(const int* __restrict__ yt,
                                                 const float* __restrict__ yp,
                                                 float* __restrict__ out) {
  const int b = blockIdx.x;
  const int tid = threadIdx.x;
  const int L = tid & 63;
  const int w = tid >> 6;  // 0 = scan consumer (alone on SIMD0), 1..3 = prod

  __shared__ uint4 ETl[4][8][64];            // 32 KB ring: 4 bufs x 8 groups
  __shared__ __align__(16) float EBl[TT];    // 4 KB: all blank probs

  const int2 lab = *(const int2*)(yt + b * LL + 2 * L);

  // consumer constants (garbage-but-unused on producer waves)
  const int labm1 = __shfl_up(lab.y, 1);
  const float s1f = ((L > 0) && (lab.x != labm1)) ? 1.0f : 0.0f;  // s=4L+1
  const float s3f = (lab.y != lab.x) ? 1.0f : 0.0f;               // s=4L+3

  // producer constants: packed-bperm gather of label cols
  const float* Pb = yp + (size_t)b * TT * CC;
  const int gxb = (lab.x >> 1) << 2, gyb = (lab.y >> 1) << 2;  // byte addr
  const int sx = lab.x & 1, sy = lab.y & 1;

  float2 vvA0, vvA1, vvA2, vvA3;  // even staging set
  float2 vvB0, vvB1, vvB2, vvB3;
  float2 vvC0, vvC1, vvC2, vvC3;
  float2 vvD0, vvD1, vvD2, vvD3;  // odd staging set
  float2 vvE0, vvE1, vvE2, vvE3;
  float2 vvF0, vvF1, vvF2, vvF3;

  // prologue: stage buffers 0,1 serially; preload buffer 2 into even set
  if (w != 0) {
    LOADBUF3(A, B, C, 0);
    COMPBUF3(A, B, C, 0);
    LOADBUF3(A, B, C, 1);
    COMPBUF3(A, B, C, 1);
    LOADBUF3(A, B, C, 2);
  }
  __syncthreads();  // buffers 0,1 published

  uint4 etA = {0, 0, 0, 0}, etB = {0, 0, 0, 0};
  float4 ebA = {0, 0, 0, 0}, ebB = {0, 0, 0, 0};
  if (w == 0) {
    etA = ((const uint4*)ETl)[L];
    ebA = *(const float4*)&EBl[0];
  }

  // virtual alpha_{-1}: state 0 = 2^100, rest 0; first step yields alpha_0
  float a0 = (w == 0 && L == 0) ? 0x1.0p100f : 0.0f;
  float a1 = 0.0f, a2 = 0.0f, a3 = 0.0f, a4 = 0.0f;
  int ell = -100;  // wave-uniform: alpha_true = a * 2^ell

  // 32 intervals x 32 steps; unrolled x2 for staging-register double-buffer.
  // Producer interval: LOADS FIRST (into the idle set — ~1500+cy before the
  // barrier's vmcnt drain), then comp the set loaded last interval.
#pragma unroll 1
  for (int kk = 0; kk < 32; kk += 2) {
    if (w == 0) {
      CONSUME(kk);
    } else {
      if (kk < 29) LOADBUF3(D, E, F, kk + 3);  // loads for buffer kk+3
      if (kk < 30) COMPBUF3(A, B, C, kk + 2);  // comp buffer kk+2
    }
    __syncthreads();
    if (w == 0) {
      CONSUME(kk + 1);
    } else {
      if (kk + 1 < 29) LOADBUF3(A, B, C, kk + 4);
      if (kk + 1 < 30) COMPBUF3(D, E, F, kk + 3);
    }
    __syncthreads();
  }

  if (tid == 63) {  // consumer wave, lane 63
    // states 255 (=a3), 256 (=a4): loglik = ln2 * (ell + log2(a3+a4))
    float s = a3 + a4;
    if (s < 1e-37f) s = 1e-37f;  // stay normal; loud-but-finite floor
    out[b] = -LN2F * ((float)ell + LOG2F(s));
  }
}

extern "C" void kernel_launch(void* const* d_in, const int* in_sizes, int n_in,
                              void* d_out, int out_size, void* d_ws,
                              size_t ws_size, hipStream_t stream) {
  (void)d_ws; (void)ws_size; (void)n_in; (void)out_size;
  const int* yt = (const int*)d_in[0];
  const float* yp = (const float*)d_in[1];
  float* out = (float*)d_out;
  const int B = in_sizes[0] / LL;  // 128
  hipLaunchKernelGGL(ctc_fused, dim3(B), dim3(256), 0, stream, yt, yp, out);
}

// Round 13
// 128.296 us; speedup vs baseline: 1.0304x; 1.0304x over previous
//
#include <hip/hip_runtime.h>

#define TT 1024
#define CC 128
#define LL 128
#define EPSF 1e-7f
#define LN2F 0.69314718055994531f

#define LOG2F(x) __builtin_amdgcn_logf(x)

typedef unsigned int uint;

template <int CTRL>
__device__ __forceinline__ int dpp_i(int old_, int x) {
  return __builtin_amdgcn_update_dpp(old_, x, CTRL, 0xf, 0xf, false);
}
// DPP with bound_ctrl: invalid lanes read 0 (for additive reductions)
template <int CTRL>
__device__ __forceinline__ float dpp0f(float x) {
  return __uint_as_float((uint)__builtin_amdgcn_update_dpp(
      0, (int)__float_as_uint(x), CTRL, 0xf, 0xf, true));
}
// shift a3 to next lane (wave_shr:1); lane 0 receives 0.0f via bound_ctrl
__device__ __forceinline__ float dpp_shr1_f32(float x) {
  return __uint_as_float((uint)__builtin_amdgcn_update_dpp(
      0, (int)__float_as_uint(x), 0x138, 0xf, 0xf, true));
}

// fp32 -> bf16 bits, round-to-nearest-even (inputs finite positive)
__device__ __forceinline__ uint bf16bits(float x) {
  uint u = __float_as_uint(x);
  return (u + 0x7fffu + ((u >> 16) & 1u)) >> 16;
}

// ---- fused CTC: producer waves feed the serial scan through LDS ----
// 128 blocks x 256 threads (4 waves). Wave 0 = the r5 consumer, UNCHANGED
// inner loop (proven 3060cy/32-step pace), ALONE on SIMD0. Waves 1..3 =
// producers staging the 4-buffer LDS ring + EB (barrier per interval).
//
// r12 post-mortem: interval still ~4740cy. Producer staging compute was
// the critical path: per row, DPP-reduce (6 dependent levels + hazard
// nops) -> readlane63 (VALU->SALU hazard) -> v_rcp -> normalize -> pack
// -> bperm was a ~200+cy SERIAL chain x 12 rows. Fix: REMOVE
// NORMALIZATION ALGEBRAICALLY. Stage raw+eps (bf16-packed, same packed
// bperm gather); alpha runs un-normalized — the consumer's existing
// power-of-2 rescale absorbs the drift (growth <= 3^16 ~ 2^25/window,
// under the 2^27 headroom above the 2^100 pin). Correct at the end:
// loglik2 = ell + log2(a3+a4) - SUM_t log2 S_t. Row sums (same DPP
// chains) now feed only a local slog accumulator (log2 via v_log_f32) —
// no readlane, no rcp, no reduce->pack dependency. Producer waves
// combine slog partials via LDS after the loop; consumer subtracts.

// one lattice step using word wv (bf16 pair) and blank prob pbf
#define CTC_STEP(wv, pbf)                                   \
  do {                                                      \
    const float p1 = __uint_as_float((wv) << 16);           \
    const float p2 = __uint_as_float((wv) & 0xffff0000u);   \
    const float pb = (pbf);                                 \
    const float p3 = dpp_shr1_f32(a3);                      \
    const float n0 = (a0 + p3) * pb;                        \
    const float n1 = __builtin_fmaf(s1f, p3, a0 + a1) * p1; \
    const float n2 = (a2 + a1) * pb;                        \
    const float n3 = __builtin_fmaf(s3f, a1, a3 + a2) * p2; \
    const float n4 = (a4 + a3) * pb;                        \
    a0 = n0; a1 = n1; a2 = n2; a3 = n3; a4 = n4;            \
  } while (0)

#define CTC_QUAD(et, eb)      \
  do {                        \
    CTC_STEP((et).x, (eb).x); \
    CTC_STEP((et).y, (eb).y); \
    CTC_STEP((et).z, (eb).z); \
    CTC_STEP((et).w, (eb).w); \
  } while (0)

// rescale wave-max exponent back to 2^100 (biased 227); e clamped so the
// correction factor stays a normal fp32 even after a catastrophic window
#define CTC_RESCALE()                                                \
  do {                                                               \
    const float m = fmaxf(fmaxf(fmaxf(a0, a1), fmaxf(a2, a3)), a4);  \
    int ke = (int)(__float_as_uint(m) >> 23);                        \
    ke = max(ke, dpp_i<0x111>(ke, ke));                              \
    ke = max(ke, dpp_i<0x112>(ke, ke));                              \
    ke = max(ke, dpp_i<0x114>(ke, ke));                              \
    ke = max(ke, dpp_i<0x118>(ke, ke));                              \
    ke = max(ke, dpp_i<0x142>(ke, ke));                              \
    ke = max(ke, dpp_i<0x143>(ke, ke));                              \
    ke = __builtin_amdgcn_readlane(ke, 63);                          \
    int e = ke - 227; /* biased_exp(max) - (127 + 100) */            \
    e = e < -127 ? -127 : e;                                         \
    const float sc = __uint_as_float((uint)(127 - e) << 23);         \
    a0 *= sc; a1 *= sc; a2 *= sc; a3 *= sc; a4 *= sc;                \
    ell += e;                                                        \
  } while (0)

// load the 4 rows of quad qg into named float2 set S
#define ST_LOAD(S, qg)                                          \
  do {                                                          \
    const float* Pq = Pb + (size_t)(qg) * 4 * CC + 2 * L;       \
    vv##S##0 = *(const float2*)(Pq + 0 * CC);                   \
    vv##S##1 = *(const float2*)(Pq + 1 * CC);                   \
    vv##S##2 = *(const float2*)(Pq + 2 * CC);                   \
    vv##S##3 = *(const float2*)(Pq + 3 * CC);                   \
  } while (0)

// publish quad qg from set S: pack bf16(raw+eps) pair, ONE bperm per
// label + half-select, one ds_write_b128; lane 63 writes blank float4.
// Row sums (DPP chains, total valid in lane 63) feed ONLY slog — off
// the staging path, no readlane/rcp, chains pipeline freely.
#define ST_COMP(S, qg)                                                      \
  do {                                                                      \
    const float2 vr0 = vv##S##0, vr1 = vv##S##1;                            \
    const float2 vr2 = vv##S##2, vr3 = vv##S##3;                            \
    const float2 vr[4] = {vr0, vr1, vr2, vr3};                              \
    float ss[4];                                                            \
    ss[0] = (vr0.x + EPSF) + (vr0.y + EPSF);                                \
    ss[1] = (vr1.x + EPSF) + (vr1.y + EPSF);                                \
    ss[2] = (vr2.x + EPSF) + (vr2.y + EPSF);                                \
    ss[3] = (vr3.x + EPSF) + (vr3.y + EPSF);                                \
    _Pragma("unroll") for (int j = 0; j < 4; ++j)                           \
        ss[j] += dpp0f<0x111>(ss[j]); /* row_shr:1 */                       \
    _Pragma("unroll") for (int j = 0; j < 4; ++j)                           \
        ss[j] += dpp0f<0x112>(ss[j]); /* row_shr:2 */                       \
    _Pragma("unroll") for (int j = 0; j < 4; ++j)                           \
        ss[j] += dpp0f<0x114>(ss[j]); /* row_shr:4 */                       \
    _Pragma("unroll") for (int j = 0; j < 4; ++j)                           \
        ss[j] += dpp0f<0x118>(ss[j]); /* row_shr:8 */                       \
    _Pragma("unroll") for (int j = 0; j < 4; ++j)                           \
        ss[j] += dpp0f<0x142>(ss[j]); /* row_bcast15 */                     \
    _Pragma("unroll") for (int j = 0; j < 4; ++j)                           \
        ss[j] += dpp0f<0x143>(ss[j]); /* row_bcast31: total in lane 63 */   \
    uint wds[4];                                                            \
    float nys[4];                                                           \
    _Pragma("unroll") for (int j = 0; j < 4; ++j) {                         \
      const float nx = vr[j].x + EPSF;                                      \
      const float ny = vr[j].y + EPSF;                                      \
      const uint pk = (bf16bits(ny) << 16) | bf16bits(nx);                  \
      const uint wx = (uint)__builtin_amdgcn_ds_bpermute(gxb, (int)pk);     \
      const uint wy = (uint)__builtin_amdgcn_ds_bpermute(gyb, (int)pk);     \
      const uint bx = sx ? (wx >> 16) : (wx & 0xffffu);                     \
      const uint by = sy ? (wy >> 16) : (wy & 0xffffu);                     \
      wds[j] = (by << 16) | bx;                                             \
      nys[j] = ny;                                                          \
      slog += LOG2F(ss[j]); /* valid in lane 63; harmless elsewhere */      \
    }                                                                       \
    uint4 val;                                                              \
    val.x = wds[0]; val.y = wds[1]; val.z = wds[2]; val.w = wds[3];         \
    *(uint4*)((char*)ETl + (((qg) >> 3) & 3) * 8192 +                       \
              ((qg) & 7) * 1024 + L * 16) = val;                            \
    if (L == 63) {                                                          \
      float4 e4;                                                            \
      e4.x = nys[0]; e4.y = nys[1]; e4.z = nys[2]; e4.w = nys[3];           \
      *(float4*)&EBl[(qg) * 4] = e4;                                        \
    }                                                                       \
  } while (0)

// per-wave quad ownership within buffer bb: q = (w-1), (w-1)+3, (w-1)+6
#define LOADBUF3(X, Y, Z, bb)         \
  do {                                \
    const int qb = (bb) * 8 + w - 1;  \
    ST_LOAD(X, qb);                   \
    ST_LOAD(Y, qb + 3);               \
    if (w < 3) ST_LOAD(Z, qb + 6);    \
  } while (0)
#define COMPBUF3(X, Y, Z, bb)         \
  do {                                \
    const int qb = (bb) * 8 + w - 1;  \
    ST_COMP(X, qb);                   \
    ST_COMP(Y, qb + 3);               \
    if (w < 3) ST_COMP(Z, qb + 6);    \
  } while (0)

// consumer interval: 8 groups of buffer kk_, 1-group-ahead A/B rotation
#define CONSUME(kk_)                                                     \
  do {                                                                   \
    const uint4* cur = (const uint4*)ETl + (size_t)((kk_) & 3) * 512;    \
    const float4* ebp = (const float4*)&EBl[(kk_) * 32];                 \
    etB = cur[1 * 64 + L]; ebB = ebp[1];                                 \
    CTC_QUAD(etA, ebA); /* g0 */                                         \
    etA = cur[2 * 64 + L]; ebA = ebp[2];                                 \
    CTC_QUAD(etB, ebB); /* g1 */                                         \
    etB = cur[3 * 64 + L]; ebB = ebp[3];                                 \
    CTC_QUAD(etA, ebA); /* g2 */                                         \
    etA = cur[4 * 64 + L]; ebA = ebp[4];                                 \
    CTC_QUAD(etB, ebB); /* g3 */                                         \
    CTC_RESCALE();                                                       \
    etB = cur[5 * 64 + L]; ebB = ebp[5];                                 \
    CTC_QUAD(etA, ebA); /* g4 */                                         \
    etA = cur[6 * 64 + L]; ebA = ebp[6];                                 \
    CTC_QUAD(etB, ebB); /* g5 */                                         \
    etB = cur[7 * 64 + L]; ebB = ebp[7];                                 \
    CTC_QUAD(etA, ebA); /* g6 */                                         \
    etA = ((const uint4*)ETl)[(size_t)(((kk_) + 1) & 3) * 512 + L];      \
    ebA = *(const float4*)&EBl[((kk_) < 31) ? ((kk_) + 1) * 32 : 1020];  \
    CTC_QUAD(etB, ebB); /* g7 */                                         \
    CTC_RESCALE();                                                       \
  } while (0)

__global__ __launch_bounds__(256) void ctc_fused(const int* __restrict__ yt,
                                                 const float* __restrict__ yp,
                                                 float* __restrict__ out) {
  const int b = blockIdx.x;
  const int tid = threadIdx.x;
  const int L = tid & 63;
  const int w = tid >> 6;  // 0 = scan consumer (alone on SIMD0), 1..3 = prod

  __shared__ uint4 ETl[4][8][64];            // 32 KB ring: 4 bufs x 8 groups
  __shared__ __align__(16) float EBl[TT];    // 4 KB: all blank probs
  __shared__ float slogsh[4];                // producer log-sum partials

  const int2 lab = *(const int2*)(yt + b * LL + 2 * L);

  // consumer constants (garbage-but-unused on producer waves)
  const int labm1 = __shfl_up(lab.y, 1);
  const float s1f = ((L > 0) && (lab.x != labm1)) ? 1.0f : 0.0f;  // s=4L+1
  const float s3f = (lab.y != lab.x) ? 1.0f : 0.0f;               // s=4L+3

  // producer constants: packed-bperm gather of label cols
  const float* Pb = yp + (size_t)b * TT * CC;
  const int gxb = (lab.x >> 1) << 2, gyb = (lab.y >> 1) << 2;  // byte addr
  const int sx = lab.x & 1, sy = lab.y & 1;

  float2 vvA0, vvA1, vvA2, vvA3;  // even staging set
  float2 vvB0, vvB1, vvB2, vvB3;
  float2 vvC0, vvC1, vvC2, vvC3;
  float2 vvD0, vvD1, vvD2, vvD3;  // odd staging set
  float2 vvE0, vvE1, vvE2, vvE3;
  float2 vvF0, vvF1, vvF2, vvF3;

  float slog = 0.0f;  // per-producer SUM_t log2 S_t (valid in lane 63)

  // prologue: stage buffers 0,1 serially; preload buffer 2 into even set
  if (w != 0) {
    LOADBUF3(A, B, C, 0);
    COMPBUF3(A, B, C, 0);
    LOADBUF3(A, B, C, 1);
    COMPBUF3(A, B, C, 1);
    LOADBUF3(A, B, C, 2);
  }
  __syncthreads();  // buffers 0,1 published

  uint4 etA = {0, 0, 0, 0}, etB = {0, 0, 0, 0};
  float4 ebA = {0, 0, 0, 0}, ebB = {0, 0, 0, 0};
  if (w == 0) {
    etA = ((const uint4*)ETl)[L];
    ebA = *(const float4*)&EBl[0];
  }

  // virtual alpha_{-1}: state 0 = 2^100, rest 0; first step yields alpha_0
  float a0 = (w == 0 && L == 0) ? 0x1.0p100f : 0.0f;
  float a1 = 0.0f, a2 = 0.0f, a3 = 0.0f, a4 = 0.0f;
  int ell = -100;  // wave-uniform: alpha_true = a * 2^ell

  // 32 intervals x 32 steps; unrolled x2 for staging-register double-buffer.
  // Producer interval: LOADS FIRST (into the idle set), then comp the set
  // loaded last interval (short, chain-free), then barrier drain.
#pragma unroll 1
  for (int kk = 0; kk < 32; kk += 2) {
    if (w == 0) {
      CONSUME(kk);
    } else {
      if (kk < 29) LOADBUF3(D, E, F, kk + 3);  // loads for buffer kk+3
      if (kk < 30) COMPBUF3(A, B, C, kk + 2);  // comp buffer kk+2
    }
    __syncthreads();
    if (w == 0) {
      CONSUME(kk + 1);
    } else {
      if (kk + 1 < 29) LOADBUF3(A, B, C, kk + 4);
      if (kk + 1 < 30) COMPBUF3(D, E, F, kk + 3);
    }
    __syncthreads();
  }

  // combine producer log-sum partials
  if (w != 0 && L == 63) slogsh[w] = slog;
  __syncthreads();

  if (tid == 63) {  // consumer wave, lane 63
    // states 255 (=a3), 256 (=a4): un-normalized loglik minus correction
    float s = a3 + a4;
    if (s < 1e-37f) s = 1e-37f;  // stay normal; loud-but-finite floor
    const float slq = slogsh[1] + slogsh[2] + slogsh[3];
    out[b] = -LN2F * ((float)ell + LOG2F(s) - slq);
  }
}

extern "C" void kernel_launch(void* const* d_in, const int* in_sizes, int n_in,
                              void* d_out, int out_size, void* d_ws,
                              size_t ws_size, hipStream_t stream) {
  (void)d_ws; (void)ws_size; (void)n_in; (void)out_size;
  const int* yt = (const int*)d_in[0];
  const float* yp = (const float*)d_in[1];
  float* out = (float*)d_out;
  const int B = in_sizes[0] / LL;  // 128
  hipLaunchKernelGGL(ctc_fused, dim3(B), dim3(256), 0, stream, yt, yp, out);
}